// Round 12
// baseline (97.119 us; speedup 1.0000x reference)
//
#include <hip/hip_runtime.h>
#include <math.h>

// MidpointMLR: B=1048576, F=64, c=1.
// out = proj( sinh( 2*z_norm * asinh( (2*(x@zu)*cosh(2b) - (1+cx2)*sinh(2b)) / max(1-cx2,eps) ) ) )

#define MLR_B 1048576

typedef __bf16 bf16x8 __attribute__((ext_vector_type(8)));
typedef float  f32x4  __attribute__((ext_vector_type(4)));

// fire-and-forget 16B global -> LDS (lane-linear dest: base + lane*16)
#define GLOAD_LDS16(g, l)                                                              \
    __builtin_amdgcn_global_load_lds(                                                  \
        (const __attribute__((address_space(1))) void*)(g),                            \
        (__attribute__((address_space(3))) void*)(l), 16, 0, 0)

// ---------------- prep: z -> z_unit bf16 fragments + per-col constants ----------------
// k-permutation shared by A and B fragments: k = 16*i + 4*hi + j.
// Column permutation: B-fragment t, mfma-col c <-> physical col p = 4c + t.
// ws layout: bytes [0,8192): zfrag[8][512] __bf16, frag (s*4+t):
//   zf[(s*4+t)*512 + (hi*16+c)*8 + e] = bf16( z_unit[k(s,e,hi)][4c+t] )
// bytes [8192,9216): f32x4 cst4[64] = {2cosh(2b), sinh(2b), 2*z_norm, 0} per physical col
__global__ __launch_bounds__(256) void mlr_prep_kernel(const float* __restrict__ z,
                                                       const float* __restrict__ bias,
                                                       void* __restrict__ wsv) {
    __bf16* zf   = (__bf16*)wsv;
    f32x4*  cst4 = (f32x4*)((char*)wsv + 8192);
    __shared__ float part[4][64];
    __shared__ float invs[64];

    const int tid = threadIdx.x;
    const int o   = tid & 63;       // physical output column
    const int kq  = tid >> 6;       // k-quarter: 16 k's each

    float n2 = 0.f;
#pragma unroll
    for (int kk = 0; kk < 16; ++kk) {
        int k = kq * 16 + kk;
        float v = z[k * 64 + o];
        n2 = fmaf(v, v, n2);
    }
    part[kq][o] = n2;
    __syncthreads();

    if (tid < 64) {
        float tot = part[0][o] + part[1][o] + part[2][o] + part[3][o];
        float zn  = fmaxf(sqrtf(tot), 1e-15f);
        invs[o] = 1.f / zn;
        float d = 2.f * bias[o];
        cst4[o] = (f32x4){2.f * coshf(d), sinhf(d), 2.f * zn, 0.f};
    }
    __syncthreads();

    const float inv = invs[o];
    const int t = o & 3, c = o >> 2;    // fragment index, mfma-col slot
#pragma unroll
    for (int kk = 0; kk < 16; ++kk) {
        int k  = kq * 16 + kk;
        float zu = z[k * 64 + o] * inv;
        int i  = k >> 4;
        int j  = k & 3;
        int hi = (k >> 2) & 3;
        int s  = i >> 1;
        int e  = ((i & 1) << 2) | j;
        zf[(s * 4 + t) * 512 + (hi * 16 + c) * 8 + e] = (__bf16)zu;   // RNE fptrunc
    }
}

// y = sinh( g * asinh(t) ) via exp2/log2 — sign-transparent: u = t+sqrt(1+t^2) > 0.
// NB: __builtin_amdgcn_logf IS v_log_f32 = log2.
__device__ __forceinline__ float poin_y(float dot, float ch2, float sh, float g,
                                        float opc, float rden) {
    float t = fmaf(dot, ch2, -(opc * sh)) * rden;
    float u = t + sqrtf(fmaf(t, t, 1.f));
    float w = __builtin_amdgcn_exp2f(g * __builtin_amdgcn_logf(u));   // u^g
    return 0.5f * (w - __builtin_amdgcn_rcpf(w));
}

struct StepMid {
    f32x4 acc[4];
    float p;        // cx2 for row lo
};

// gemm phase: cx2 + bf16 pack + 8 MFMA. c0..c3 die here.
__device__ __forceinline__ StepMid mlr_gemm(f32x4 c0, f32x4 c1, f32x4 c2, f32x4 c3,
                                            const bf16x8* bfr) {
    StepMid m;
    float p = 0.f;
#pragma unroll
    for (int j = 0; j < 4; ++j) {
        p = fmaf(c0[j], c0[j], p); p = fmaf(c1[j], c1[j], p);
        p = fmaf(c2[j], c2[j], p); p = fmaf(c3[j], c3[j], p);
    }
    p += __shfl_xor(p, 16);
    p += __shfl_xor(p, 32);
    m.p = p;

    bf16x8 a0, a1;
#pragma unroll
    for (int j = 0; j < 4; ++j) {
        a0[j]     = (__bf16)c0[j];
        a0[4 + j] = (__bf16)c1[j];
        a1[j]     = (__bf16)c2[j];
        a1[4 + j] = (__bf16)c3[j];
    }

#pragma unroll
    for (int t = 0; t < 4; ++t) {
        m.acc[t] = (f32x4){0.f, 0.f, 0.f, 0.f};
        m.acc[t] = __builtin_amdgcn_mfma_f32_16x16x32_bf16(a0, bfr[t],     m.acc[t], 0, 0, 0);
        m.acc[t] = __builtin_amdgcn_mfma_f32_16x16x32_bf16(a1, bfr[4 + t], m.acc[t], 0, 0, 0);
    }
    return m;
}

// finish phase: transcendental epilogue + projection + nt stores.
// C/D map col=lo, row=4*hi+reg; acc[t][r] = physical col 4*lo+t.
__device__ __forceinline__ void mlr_fin(const StepMid& m, const f32x4* cc,
                                        int lo, int hi, char* ob) {
    f32x4 yv[4]; float S[4];
#pragma unroll
    for (int r = 0; r < 4; ++r) {
        float cxr  = __shfl(m.p, hi * 4 + r);          // cx2 of row 4*hi+r
        float opc  = 1.f + cxr;
        float rden = __builtin_amdgcn_rcpf(fmaxf(1.f - cxr, 1e-15f));
        float s0 = 0.f;
        f32x4 y;
#pragma unroll
        for (int t = 0; t < 4; ++t) {
            float v = poin_y(m.acc[t][r], cc[t].x, cc[t].y, cc[t].z, opc, rden);
            y[t] = v;
            s0 = fmaf(v, v, s0);
        }
        yv[r] = y;
        S[r] = s0;
    }
#pragma unroll
    for (int r = 0; r < 4; ++r) {
        float s0 = S[r];
        s0 += __shfl_xor(s0, 1);
        s0 += __shfl_xor(s0, 2);
        s0 += __shfl_xor(s0, 4);
        s0 += __shfl_xor(s0, 8);                       // sum over all 64 cols of row
        float scale = __builtin_amdgcn_rcpf(1.f + sqrtf(1.f + s0));
        f32x4 y = yv[r];
        y[0] *= scale; y[1] *= scale; y[2] *= scale; y[3] *= scale;
        yv[r] = y;
    }
#pragma unroll
    for (int r = 0; r < 4; ++r)
        __builtin_nontemporal_store(yv[r], (f32x4*)(ob + r * 256));
}

// ---------------- main: fire-and-forget global->LDS staging, 2 steps/wave ----------------
// Per wave: 8 KB x-tile (32 rows) staged via 8 global_load_lds_dwordx4 (no VGPRs held,
// no issue-blocking), one vmcnt(0), then both steps compute from LDS.
// LDS slot map: row r stores chunk (s^r) at slot s (pre-swizzled global source, rule #21);
// ds_read applies the same XOR -> stride-256B row reads spread across bank groups.
__global__ __launch_bounds__(256) void mlr_main_kernel(const float* __restrict__ x,
                                                       const void* __restrict__ wsv,
                                                       float* __restrict__ out) {
    __shared__ char xs[32768];          // 4 waves x 8 KB, no cross-wave sharing
    const __bf16* zf   = (const __bf16*)wsv;
    const f32x4*  cst4 = (const f32x4*)((const char*)wsv + 8192);
    const int tid  = threadIdx.x;
    const int lane = tid & 63;
    const int lo   = lane & 15;     // A-row / C-col index
    const int hi   = lane >> 4;     // k-group / C-row-group
    const int w    = tid >> 6;
    const int wv   = blockIdx.x * 4 + w;
    const size_t rowbase = (size_t)wv * 32;            // 2 steps x 16 rows

    char* wbase = xs + w * 8192;
    const char* xg = (const char*)x;

    // stage both steps' x rows: instr n covers rows (n&3)*4 .. +3 of step n>>2
    // lane (s=lo, rr=hi): dest = wbase + n*1024 + lane*16 = row r, slot s; content chunk s^r
#pragma unroll
    for (int n = 0; n < 8; ++n) {
        const int st = n >> 2, n2 = n & 3;
        const int r  = n2 * 4 + hi;                    // local row 0..15
        const int ck = lo ^ r;                         // chunk stored at slot lo
        const char* src = xg + (rowbase + (size_t)(st * 16 + r)) * 256 + ck * 16;
        GLOAD_LDS16(src, wbase + n * 1024);
    }

    // B fragments (z_unit) + per-col constants (regular loads, L2-resident)
    bf16x8 bfr[8];
#pragma unroll
    for (int i = 0; i < 8; ++i)
        bfr[i] = *(const bf16x8*)((const char*)zf + i * 1024 + lane * 16);
    f32x4 cc[4];
#pragma unroll
    for (int t = 0; t < 4; ++t) cc[t] = cst4[4 * lo + t];

    // drain staging (and bfr/cc) once; no barrier needed (wave-private LDS region)
    asm volatile("s_waitcnt vmcnt(0)" ::: "memory");
    __builtin_amdgcn_sched_barrier(0);

    char* ob = (char*)out + (rowbase + (size_t)hi * 4) * 256 + lo * 16;

#pragma unroll
    for (int st = 0; st < 2; ++st) {
        const char* sb = wbase + st * 4096 + lo * 256;
        f32x4 c0 = *(const f32x4*)(sb + ((0  + hi) ^ lo) * 16);   // chunk 4*0+hi
        f32x4 c1 = *(const f32x4*)(sb + ((4  + hi) ^ lo) * 16);   // chunk 4*1+hi
        f32x4 c2 = *(const f32x4*)(sb + ((8  + hi) ^ lo) * 16);   // chunk 4*2+hi
        f32x4 c3 = *(const f32x4*)(sb + ((12 + hi) ^ lo) * 16);   // chunk 4*3+hi
        StepMid m = mlr_gemm(c0, c1, c2, c3, bfr);
        mlr_fin(m, cc, lo, hi, ob + st * 4096);
    }
}

extern "C" void kernel_launch(void* const* d_in, const int* in_sizes, int n_in,
                              void* d_out, int out_size, void* d_ws, size_t ws_size,
                              hipStream_t stream) {
    const float* x    = (const float*)d_in[0];
    const float* z    = (const float*)d_in[1];
    const float* bias = (const float*)d_in[2];
    float* out = (float*)d_out;

    mlr_prep_kernel<<<dim3(1), dim3(256), 0, stream>>>(z, bias, d_ws);
    mlr_main_kernel<<<dim3(8192), dim3(256), 0, stream>>>(x, d_ws, out);
}

// Round 13
// 95.584 us; speedup vs baseline: 1.0161x; 1.0161x over previous
//
#include <hip/hip_runtime.h>
#include <math.h>

// MidpointMLR: B=1048576, F=64, c=1. Single fused kernel (prep folded in per block).
// out = proj( sinh( 2*z_norm * asinh( (2*(x@zu)*cosh(2b) - (1+cx2)*sinh(2b)) / max(1-cx2,eps) ) ) )

#define MLR_B 1048576

typedef __bf16 bf16x8 __attribute__((ext_vector_type(8)));
typedef float  f32x4  __attribute__((ext_vector_type(4)));

#define LOG2E 1.4426950408889634f

// y = sinh( g * asinh(t) ) via exp2/log2 — sign-transparent: u = t+sqrt(1+t^2) > 0.
// NB: __builtin_amdgcn_logf IS v_log_f32 = log2.
__device__ __forceinline__ float poin_y(float dot, float ch2, float sh, float g,
                                        float opc, float rden) {
    float t = fmaf(dot, ch2, -(opc * sh)) * rden;
    float u = t + sqrtf(fmaf(t, t, 1.f));
    float w = __builtin_amdgcn_exp2f(g * __builtin_amdgcn_logf(u));   // u^g
    return 0.5f * (w - __builtin_amdgcn_rcpf(w));
}

struct StepMid {
    f32x4 acc[4];
    float p;        // cx2 for row lo
};

// gemm phase: cx2 + bf16 pack + 8 MFMA. c0..c3 die here.
__device__ __forceinline__ StepMid mlr_gemm(f32x4 c0, f32x4 c1, f32x4 c2, f32x4 c3,
                                            const bf16x8* bfr) {
    StepMid m;
    float p = 0.f;
#pragma unroll
    for (int j = 0; j < 4; ++j) {
        p = fmaf(c0[j], c0[j], p); p = fmaf(c1[j], c1[j], p);
        p = fmaf(c2[j], c2[j], p); p = fmaf(c3[j], c3[j], p);
    }
    p += __shfl_xor(p, 16);
    p += __shfl_xor(p, 32);
    m.p = p;

    bf16x8 a0, a1;
#pragma unroll
    for (int j = 0; j < 4; ++j) {
        a0[j]     = (__bf16)c0[j];
        a0[4 + j] = (__bf16)c1[j];
        a1[j]     = (__bf16)c2[j];
        a1[4 + j] = (__bf16)c3[j];
    }

#pragma unroll
    for (int t = 0; t < 4; ++t) {
        m.acc[t] = (f32x4){0.f, 0.f, 0.f, 0.f};
        m.acc[t] = __builtin_amdgcn_mfma_f32_16x16x32_bf16(a0, bfr[t],     m.acc[t], 0, 0, 0);
        m.acc[t] = __builtin_amdgcn_mfma_f32_16x16x32_bf16(a1, bfr[4 + t], m.acc[t], 0, 0, 0);
    }
    return m;
}

// finish phase: transcendental epilogue + projection + nt stores.
// C/D map col=lo, row=4*hi+reg; acc[t][r] = physical col 4*lo+t.
__device__ __forceinline__ void mlr_fin(const StepMid& m, const f32x4* cc,
                                        int lo, int hi, char* ob) {
    f32x4 yv[4]; float S[4];
#pragma unroll
    for (int r = 0; r < 4; ++r) {
        float cxr  = __shfl(m.p, hi * 4 + r);          // cx2 of row 4*hi+r
        float opc  = 1.f + cxr;
        float rden = __builtin_amdgcn_rcpf(fmaxf(1.f - cxr, 1e-15f));
        float s0 = 0.f;
        f32x4 y;
#pragma unroll
        for (int t = 0; t < 4; ++t) {
            float v = poin_y(m.acc[t][r], cc[t].x, cc[t].y, cc[t].z, opc, rden);
            y[t] = v;
            s0 = fmaf(v, v, s0);
        }
        yv[r] = y;
        S[r] = s0;
    }
#pragma unroll
    for (int r = 0; r < 4; ++r) {
        float s0 = S[r];
        s0 += __shfl_xor(s0, 1);
        s0 += __shfl_xor(s0, 2);
        s0 += __shfl_xor(s0, 4);
        s0 += __shfl_xor(s0, 8);                       // sum over all 64 cols of row
        float scale = __builtin_amdgcn_rcpf(1.f + sqrtf(1.f + s0));
        f32x4 y = yv[r];
        y[0] *= scale; y[1] *= scale; y[2] *= scale; y[3] *= scale;
        yv[r] = y;
    }
#pragma unroll
    for (int r = 0; r < 4; ++r)
        __builtin_nontemporal_store(yv[r], (f32x4*)(ob + r * 256));
}

// ---------------- fused main: per-block z-prep (L2-resident) + 2 MFMA steps/wave ----
// Load order fixes vmcnt semantics: z(16) -> bias(4) -> x(4): prep data ready at
// vmcnt(4) while x loads stay in flight across the raw barriers (no vmcnt drain).
__global__ __launch_bounds__(256, 4) void mlr_fused_kernel(const float* __restrict__ x,
                                                           const float* __restrict__ z,
                                                           const float* __restrict__ bias,
                                                           float* __restrict__ out) {
    __shared__ float  part[4][64];
    __shared__ __bf16 zfl[4096];    // bf16 z_unit fragments, frag i: zfl[i*512 + lane*8]

    const int tid  = threadIdx.x;
    const int lane = tid & 63;
    const int lo   = lane & 15;     // A-row / C-col index
    const int hi   = lane >> 4;     // k-group / C-row-group
    const int w    = tid >> 6;
    const int o    = lane;          // prep column (== lane)
    const int kq   = w;             // prep k-quarter
    const int wv   = blockIdx.x * 4 + w;
    const size_t rowbase = (size_t)wv * 32;            // 2 steps x 16 rows

    // ---- issue loads: z first, bias, then step-0 x (stays outstanding) ----
    float zv[16];
#pragma unroll
    for (int kk = 0; kk < 16; ++kk)
        zv[kk] = z[(kq * 16 + kk) * 64 + o];           // coalesced, L2-resident

    float bb[4];
#pragma unroll
    for (int t = 0; t < 4; ++t) bb[t] = bias[4 * lo + t];

    const char* xb = (const char*)x + (rowbase + (size_t)lo) * 256 + hi * 16;
    f32x4 c0 = *(const f32x4*)(xb + 0);
    f32x4 c1 = *(const f32x4*)(xb + 64);
    f32x4 c2 = *(const f32x4*)(xb + 128);
    f32x4 c3 = *(const f32x4*)(xb + 192);

    // ---- prep: column partial norms (needs zv only -> vmcnt(8)-ish) ----
    float n2 = 0.f;
#pragma unroll
    for (int kk = 0; kk < 16; ++kk) n2 = fmaf(zv[kk], zv[kk], n2);
    part[kq][o] = n2;
    asm volatile("s_waitcnt lgkmcnt(0)" ::: "memory");
    __builtin_amdgcn_s_barrier();

    float tot_own = part[0][o] + part[1][o] + part[2][o] + part[3][o];
    float zn_own  = fmaxf(sqrtf(tot_own), 1e-15f);
    float inv     = 1.f / zn_own;

    // per-col epilogue constants for physical cols 4lo+t, built in-register via shfl
    f32x4 cc[4];
#pragma unroll
    for (int t = 0; t < 4; ++t) {
        float tot_c = __shfl(tot_own, 4 * lo + t);
        float zn_c  = fmaxf(sqrtf(tot_c), 1e-15f);
        float e  = __builtin_amdgcn_exp2f(2.f * bb[t] * LOG2E);   // e^{2b}
        float re = __builtin_amdgcn_rcpf(e);
        cc[t] = (f32x4){e + re, 0.5f * (e - re), 2.f * zn_c, 0.f}; // {2cosh, sinh, 2zn}
    }

    // ---- z_unit bf16 fragments -> LDS (same layout as old ws zf) ----
    {
        const int tf = o & 3, cs = o >> 2;    // fragment index, mfma-col slot
#pragma unroll
        for (int kk = 0; kk < 16; ++kk) {
            int k  = kq * 16 + kk;
            float zu = zv[kk] * inv;
            int i  = k >> 4;
            int j  = k & 3;
            int h2 = (k >> 2) & 3;
            int s  = i >> 1;
            int e  = ((i & 1) << 2) | j;
            zfl[(s * 4 + tf) * 512 + (h2 * 16 + cs) * 8 + e] = (__bf16)zu;  // RNE
        }
    }
    asm volatile("s_waitcnt lgkmcnt(0)" ::: "memory");
    __builtin_amdgcn_s_barrier();

    // ---- B fragments from LDS ----
    bf16x8 bfr[8];
#pragma unroll
    for (int i = 0; i < 8; ++i)
        bfr[i] = *(const bf16x8*)((const char*)zfl + i * 1024 + lane * 16);

    char* ob = (char*)out + (rowbase + (size_t)hi * 4) * 256 + lo * 16;

    // step 0 (x already in flight since prologue)
    StepMid m0 = mlr_gemm(c0, c1, c2, c3, bfr);

    // step 1 loads: issued now, latency hidden under step-0 epilogue
    f32x4 d0 = *(const f32x4*)(xb + 4096 + 0);
    f32x4 d1 = *(const f32x4*)(xb + 4096 + 64);
    f32x4 d2 = *(const f32x4*)(xb + 4096 + 128);
    f32x4 d3 = *(const f32x4*)(xb + 4096 + 192);

    mlr_fin(m0, cc, lo, hi, ob);

    StepMid m1 = mlr_gemm(d0, d1, d2, d3, bfr);
    mlr_fin(m1, cc, lo, hi, ob + 4096);
}

extern "C" void kernel_launch(void* const* d_in, const int* in_sizes, int n_in,
                              void* d_out, int out_size, void* d_ws, size_t ws_size,
                              hipStream_t stream) {
    const float* x    = (const float*)d_in[0];
    const float* z    = (const float*)d_in[1];
    const float* bias = (const float*)d_in[2];
    float* out = (float*)d_out;

    mlr_fused_kernel<<<dim3(8192), dim3(256), 0, stream>>>(x, z, bias, out);
}